// Round 14
// baseline (134.233 us; speedup 1.0000x reference)
//
#include <hip/hip_runtime.h>

// Path signature M=4, d=10, L=256, B=2048 — MFMA formulation, round 14.
// Math/numerics IDENTICAL to round 11 (absmax 13): P rows split-packed
// [a_hi,a_lo,b_hi,b_lo], Q rows plain [u,u,w,w] / vcol [v,v,0,0].
// Structure: double-buffered P/Q, ONE barrier per chunk.
// ROUND-14 FIX: rounds 12/13 read xs (chain init: c1,c2,xL2) BEFORE the
// staging barrier — cross-wave init race, absmax 470/285. Barrier restored
// between xs staging and chain init. That was the only bug; dbuf rotation is
// race-free (write(buf)@ch+2 separated from read(buf)@ch by end-of-ch barrier,
// and __syncthreads drains lgkmcnt).
// Slot-major [slot][112 rows][16B]: conflict-free b128 reads+writes.

#define SIG 11110

typedef short bf16x8 __attribute__((ext_vector_type(8)));
typedef float f32x4  __attribute__((ext_vector_type(4)));

__device__ __forceinline__ unsigned cvt_pk2(float lo, float hi) {
    unsigned r;
    asm("v_cvt_pk_bf16_f32 %0, %1, %2" : "=v"(r) : "v"(lo), "v"(hi));
    return r;
}
// (bf16_hi(a) | bf16(a - hi)<<16), hi = truncated-to-bf16 (exact residual)
__device__ __forceinline__ unsigned split_pack(float a) {
    const float hi = __uint_as_float(__float_as_uint(a) & 0xFFFF0000u);
    return cvt_pk2(hi, a - hi);
}

template<int MI, int NI>
__device__ __forceinline__ void consume(const unsigned* __restrict__ Pb,
                                        const unsigned* __restrict__ Qb,
                                        int r0, int c0, int lane,
                                        f32x4 (&acc)[4][4]) {
    const int slot = lane >> 4, rr = lane & 15;
    bf16x8 Bf[4];
    #pragma unroll
    for (int ni = 0; ni < NI; ++ni)
        Bf[ni] = *(const bf16x8*)(Qb + slot * 448 + (c0 + ni * 16 + rr) * 4);
    #pragma unroll
    for (int mi = 0; mi < MI; ++mi) {
        const bf16x8 Af = *(const bf16x8*)(Pb + slot * 448 + (r0 + mi * 16 + rr) * 4);
        #pragma unroll
        for (int ni = 0; ni < NI; ++ni)
            acc[mi][ni] = __builtin_amdgcn_mfma_f32_16x16x32_bf16(Af, Bf[ni], acc[mi][ni], 0, 0, 0);
    }
}

__global__ __launch_bounds__(256, 3)
void sig_mfma7(const float* __restrict__ xg, float* __restrict__ out) {
    __shared__ float    xs[2560];          // path [t*10+dim]           10240 B
    __shared__ unsigned Pl[2][4 * 448];    // dbuf [slot][112 rows][4w] 14336 B
    __shared__ unsigned Ql[2][4 * 448];    //                           14336 B

    const int tid  = threadIdx.x;
    const int b    = blockIdx.x;
    const int lane = tid & 63;
    const int wv   = tid >> 6;
    const float* __restrict__ xb = xg + (size_t)b * 2560;

    // stage path (coalesced) + zero pads (P rows 100..111, Q rows 110..111; both bufs)
    #pragma unroll
    for (int r = 0; r < 10; ++r) xs[r * 256 + tid] = xb[r * 256 + tid];
    for (int e = tid; e < 384; e += 256) {
        const int buf = e / 192, r = e % 192, slot = r / 48, rem = r % 48;
        Pl[buf][slot * 448 + (100 + rem / 4) * 4 + (rem & 3)] = 0u;
    }
    if (tid < 64) {
        const int buf = tid / 32, r = tid % 32, slot = r / 8, rem = r % 8;
        Ql[buf][slot * 448 + (110 + rem / 4) * 4 + (rem & 3)] = 0u;
    }
    __syncthreads();   // staging visible BEFORE any xs read (r12/r13 bug was here)

    // roles: waves 0-1 = pair scan -> P ; waves 2-3 = closed-form -> Q
    const bool isPair = (tid < 100);
    const int  qrow   = tid - 128;
    const bool isCell = (qrow >= 0) && (qrow < 100);
    const bool isVcol = (qrow >= 100) && (qrow < 110);

    int i1 = 0, i2 = 0;
    if (isPair)      { i1 = tid / 10;  i2 = tid - i1 * 10; }
    else if (isCell) { i1 = qrow / 10; i2 = qrow - i1 * 10; }
    else if (isVcol) { i1 = qrow - 100; i2 = i1; }

    float c1 = xs[i1], c2 = xs[i2];             // chains x_t[i1], x_t[i2]
    const float x0i = c1;
    const float xL2 = xs[2550 + i2];            // cells: x_L[l]
    float Ds = 0.f;                             // pairs: running S2

    f32x4 acc[4][4];
    #pragma unroll
    for (int mi = 0; mi < 4; ++mi)
        #pragma unroll
        for (int ni = 0; ni < 4; ++ni) acc[mi][ni] = (f32x4){0.f, 0.f, 0.f, 0.f};

    auto produce = [&](int ch, unsigned* Pb, unsigned* Qb) {
        if (isPair) {
            unsigned q0 = 0, q1 = 0;
            #pragma unroll
            for (int tl = 0; tl < 8; ++tl) {
                const int  t     = ch * 8 + tl;
                const bool valid = (t < 255);
                const int  tt    = valid ? t : 254;
                const float n1 = xs[(tt + 1) * 10 + i1];
                const float n2 = xs[(tt + 1) * 10 + i2];
                const float vi = n1 - c1, vj = n2 - c2;
                const float s1f  = c1 - x0i;
                const float vivj = vi * vj;
                const float t1   = s1f * vj;
                float a  = fmaf(vivj, 1.f/6.f,  fmaf(t1, 0.5f,    Ds));
                float bb = fmaf(vivj, 1.f/24.f, fmaf(t1, 1.f/6.f, 0.5f * Ds));
                if (!valid) { a = 0.f; bb = 0.f; }
                const unsigned pa = split_pack(a), pb = split_pack(bb);
                if (valid) { Ds = fmaf(vj, fmaf(vi, 0.5f, s1f), Ds); c1 = n1; c2 = n2; }
                if ((tl & 1) == 0) { q0 = pa; q1 = pb; }
                else *(uint4*)&Pb[(tl >> 1) * 448 + tid * 4] = make_uint4(q0, q1, pa, pb);
            }
        } else if (isCell) {
            unsigned q0 = 0, q1 = 0;
            #pragma unroll
            for (int tl = 0; tl < 8; ++tl) {
                const int  t     = ch * 8 + tl;
                const bool valid = (t < 255);
                const int  tt    = valid ? t : 254;
                const float n1 = xs[(tt + 1) * 10 + i1];
                const float n2 = xs[(tt + 1) * 10 + i2];
                const float vk = n1 - c1, vl = n2 - c2;
                float u = vk * (xL2 - n2);
                float w = vk * vl;
                if (!valid) { u = 0.f; w = 0.f; }
                const unsigned pu = cvt_pk2(u, u), pw = cvt_pk2(w, w);
                if (valid) { c1 = n1; c2 = n2; }
                if ((tl & 1) == 0) { q0 = pu; q1 = pw; }
                else *(uint4*)&Qb[(tl >> 1) * 448 + qrow * 4] = make_uint4(q0, q1, pu, pw);
            }
        } else if (isVcol) {
            unsigned q0 = 0;
            #pragma unroll
            for (int tl = 0; tl < 8; ++tl) {
                const int  t     = ch * 8 + tl;
                const bool valid = (t < 255);
                const int  tt    = valid ? t : 254;
                const float n1 = xs[(tt + 1) * 10 + i1];
                float v = n1 - c1;
                if (!valid) v = 0.f;
                const unsigned pv = cvt_pk2(v, v);
                if (valid) c1 = n1;
                if ((tl & 1) == 0) q0 = pv;
                else *(uint4*)&Qb[(tl >> 1) * 448 + qrow * 4] = make_uint4(q0, 0u, pv, 0u);
            }
        }
    };

    produce(0, Pl[0], Ql[0]);
    __syncthreads();

    for (int ch = 0; ch < 32; ++ch) {
        const unsigned* Pb = Pl[ch & 1];
        const unsigned* Qb = Ql[ch & 1];
        if      (wv == 0) consume<3, 3>(Pb, Qb, 64, 64, lane, acc);   //  9 tiles
        else if (wv == 1) consume<3, 4>(Pb, Qb, 64,  0, lane, acc);   // 12
        else if (wv == 2) consume<4, 3>(Pb, Qb,  0, 64, lane, acc);   // 12
        else              consume<4, 4>(Pb, Qb,  0,  0, lane, acc);   // 16
        if (ch < 31) produce(ch + 1, Pl[(ch + 1) & 1], Ql[(ch + 1) & 1]);
        __syncthreads();   // single barrier/chunk: separates read@ch from write@ch+2
    }

    // epilogue: [S1(10) | S2(100) | S3(1000) | S4(10000)]
    const size_t base = (size_t)b * SIG;
    if (tid < 10)  out[base + tid] = xs[2550 + tid] - xs[tid];   // S1 exact
    if (isPair)    out[base + 10 + tid] = Ds;                    // S2 exact

    const int r0 = (wv & 2) ? 0 : 64;
    const int c0 = (wv & 1) ? 0 : 64;
    #pragma unroll
    for (int mi = 0; mi < 4; ++mi) {
        #pragma unroll
        for (int ni = 0; ni < 4; ++ni) {
            #pragma unroll
            for (int r = 0; r < 4; ++r) {
                const int m = r0 + mi * 16 + (lane >> 4) * 4 + r;
                const int n = c0 + ni * 16 + (lane & 15);
                if (m < 100) {
                    if (n < 100)      out[base + 1110 + m * 100 + n]         = acc[mi][ni][r];
                    else if (n < 110) out[base + 110  + m * 10  + (n - 100)] = acc[mi][ni][r];
                }
            }
        }
    }
}

extern "C" void kernel_launch(void* const* d_in, const int* in_sizes, int n_in,
                              void* d_out, int out_size, void* d_ws, size_t ws_size,
                              hipStream_t stream) {
    const float* x = (const float*)d_in[0];
    float* out = (float*)d_out;
    const int B = in_sizes[0] / 2560;   // 2048 batches, one block each
    sig_mfma7<<<B, 256, 0, stream>>>(x, out);
}

// Round 15
// 127.934 us; speedup vs baseline: 1.0492x; 1.0492x over previous
//
#include <hip/hip_runtime.h>

// Path signature M=4, d=10, L=256, B=2048 — MFMA formulation, round 15.
// Math identical to r11/r14 (absmax 13): P rows [a_hi,a_lo,b_hi,b_lo] split-
// packed, Q rows [u,u,w,w] / vcol [v,v,0,0]. C[112,112]=P^T Q, K=1024.
// Structure = r14 (dbuf + 1 barrier/chunk — NOTE: r11's single-buffer loop had
// a latent cross-wave produce/consume race; dbuf is correctness-load-bearing).
// ROUND-15: (1) tail-split — produce_t<8> for chunks 0..30 with NO validity
// selects/clamps; produce_t<7> only for chunk 31 (compile-time per-tl valid).
// (2) dDs = fma(0.5,vivj,t1) reuses existing terms (was vj*(vi/2+s1f)).
// Slot-major [slot][112 rows][16B]: conflict-free b128 reads+writes.

#define SIG 11110

typedef short bf16x8 __attribute__((ext_vector_type(8)));
typedef float f32x4  __attribute__((ext_vector_type(4)));

__device__ __forceinline__ unsigned cvt_pk2(float lo, float hi) {
    unsigned r;
    asm("v_cvt_pk_bf16_f32 %0, %1, %2" : "=v"(r) : "v"(lo), "v"(hi));
    return r;
}
// (bf16_hi(a) | bf16(a - hi)<<16), hi = truncated-to-bf16 (exact residual)
__device__ __forceinline__ unsigned split_pack(float a) {
    const float hi = __uint_as_float(__float_as_uint(a) & 0xFFFF0000u);
    return cvt_pk2(hi, a - hi);
}

template<int MI, int NI>
__device__ __forceinline__ void consume(const unsigned* __restrict__ Pb,
                                        const unsigned* __restrict__ Qb,
                                        int r0, int c0, int lane,
                                        f32x4 (&acc)[4][4]) {
    const int slot = lane >> 4, rr = lane & 15;
    bf16x8 Bf[4];
    #pragma unroll
    for (int ni = 0; ni < NI; ++ni)
        Bf[ni] = *(const bf16x8*)(Qb + slot * 448 + (c0 + ni * 16 + rr) * 4);
    #pragma unroll
    for (int mi = 0; mi < MI; ++mi) {
        const bf16x8 Af = *(const bf16x8*)(Pb + slot * 448 + (r0 + mi * 16 + rr) * 4);
        #pragma unroll
        for (int ni = 0; ni < NI; ++ni)
            acc[mi][ni] = __builtin_amdgcn_mfma_f32_16x16x32_bf16(Af, Bf[ni], acc[mi][ni], 0, 0, 0);
    }
}

// NV = number of valid t's in this chunk (8 for chunks 0..30, 7 for chunk 31).
template<int NV>
__device__ __forceinline__ void produce_t(int ch, const float* __restrict__ xs,
                                          unsigned* __restrict__ Pb,
                                          unsigned* __restrict__ Qb,
                                          bool isPair, bool isCell, bool isVcol,
                                          int tid, int qrow, int i1, int i2,
                                          float x0i, float xL2,
                                          float& c1, float& c2, float& Ds) {
    if (isPair) {
        unsigned q0 = 0, q1 = 0;
        #pragma unroll
        for (int tl = 0; tl < 8; ++tl) {
            unsigned pa, pb;
            if (tl < NV) {                       // compile-time condition
                const float n1 = xs[(ch * 8 + tl + 1) * 10 + i1];
                const float n2 = xs[(ch * 8 + tl + 1) * 10 + i2];
                const float vi = n1 - c1, vj = n2 - c2;
                const float s1f  = c1 - x0i;
                const float vivj = vi * vj;
                const float t1   = s1f * vj;
                const float a  = fmaf(vivj, 1.f/6.f,  fmaf(t1, 0.5f,    Ds));
                const float bb = fmaf(vivj, 1.f/24.f, fmaf(t1, 1.f/6.f, 0.5f * Ds));
                pa = split_pack(a); pb = split_pack(bb);
                Ds += fmaf(0.5f, vivj, t1);      // dDs = vj*(vi/2+s1f), reused terms
                c1 = n1; c2 = n2;
            } else { pa = 0u; pb = 0u; }
            if ((tl & 1) == 0) { q0 = pa; q1 = pb; }
            else *(uint4*)&Pb[(tl >> 1) * 448 + tid * 4] = make_uint4(q0, q1, pa, pb);
        }
    } else if (isCell) {
        unsigned q0 = 0, q1 = 0;
        #pragma unroll
        for (int tl = 0; tl < 8; ++tl) {
            unsigned pu, pw;
            if (tl < NV) {
                const float n1 = xs[(ch * 8 + tl + 1) * 10 + i1];
                const float n2 = xs[(ch * 8 + tl + 1) * 10 + i2];
                const float vk = n1 - c1, vl = n2 - c2;
                const float u = vk * (xL2 - n2);
                const float w = vk * vl;
                pu = cvt_pk2(u, u); pw = cvt_pk2(w, w);
                c1 = n1; c2 = n2;
            } else { pu = 0u; pw = 0u; }
            if ((tl & 1) == 0) { q0 = pu; q1 = pw; }
            else *(uint4*)&Qb[(tl >> 1) * 448 + qrow * 4] = make_uint4(q0, q1, pu, pw);
        }
    } else if (isVcol) {
        unsigned q0 = 0;
        #pragma unroll
        for (int tl = 0; tl < 8; ++tl) {
            unsigned pv;
            if (tl < NV) {
                const float n1 = xs[(ch * 8 + tl + 1) * 10 + i1];
                pv = cvt_pk2(n1 - c1, n1 - c1);
                c1 = n1;
            } else pv = 0u;
            if ((tl & 1) == 0) q0 = pv;
            else *(uint4*)&Qb[(tl >> 1) * 448 + qrow * 4] = make_uint4(q0, 0u, pv, 0u);
        }
    }
}

__global__ __launch_bounds__(256, 3)
void sig_mfma8(const float* __restrict__ xg, float* __restrict__ out) {
    __shared__ float    xs[2560];          // path [t*10+dim]           10240 B
    __shared__ unsigned Pl[2][4 * 448];    // dbuf [slot][112 rows][4w] 14336 B
    __shared__ unsigned Ql[2][4 * 448];    //                           14336 B

    const int tid  = threadIdx.x;
    const int b    = blockIdx.x;
    const int lane = tid & 63;
    const int wv   = tid >> 6;
    const float* __restrict__ xb = xg + (size_t)b * 2560;

    // stage path (coalesced) + zero pads (P rows 100..111, Q rows 110..111; both bufs)
    #pragma unroll
    for (int r = 0; r < 10; ++r) xs[r * 256 + tid] = xb[r * 256 + tid];
    for (int e = tid; e < 384; e += 256) {
        const int buf = e / 192, r = e % 192, slot = r / 48, rem = r % 48;
        Pl[buf][slot * 448 + (100 + rem / 4) * 4 + (rem & 3)] = 0u;
    }
    if (tid < 64) {
        const int buf = tid / 32, r = tid % 32, slot = r / 8, rem = r % 8;
        Ql[buf][slot * 448 + (110 + rem / 4) * 4 + (rem & 3)] = 0u;
    }
    __syncthreads();   // staging visible BEFORE any xs read (r12/r13 bug)

    // roles: waves 0-1 = pair scan -> P ; waves 2-3 = closed-form -> Q
    const bool isPair = (tid < 100);
    const int  qrow   = tid - 128;
    const bool isCell = (qrow >= 0) && (qrow < 100);
    const bool isVcol = (qrow >= 100) && (qrow < 110);

    int i1 = 0, i2 = 0;
    if (isPair)      { i1 = tid / 10;  i2 = tid - i1 * 10; }
    else if (isCell) { i1 = qrow / 10; i2 = qrow - i1 * 10; }
    else if (isVcol) { i1 = qrow - 100; i2 = i1; }

    float c1 = xs[i1], c2 = xs[i2];             // chains x_t[i1], x_t[i2]
    const float x0i = c1;
    const float xL2 = xs[2550 + i2];            // cells: x_L[l]
    float Ds = 0.f;                             // pairs: running S2

    f32x4 acc[4][4];
    #pragma unroll
    for (int mi = 0; mi < 4; ++mi)
        #pragma unroll
        for (int ni = 0; ni < 4; ++ni) acc[mi][ni] = (f32x4){0.f, 0.f, 0.f, 0.f};

    produce_t<8>(0, xs, Pl[0], Ql[0], isPair, isCell, isVcol,
                 tid, qrow, i1, i2, x0i, xL2, c1, c2, Ds);
    __syncthreads();

    for (int ch = 0; ch < 32; ++ch) {
        const unsigned* Pb = Pl[ch & 1];
        const unsigned* Qb = Ql[ch & 1];
        if      (wv == 0) consume<3, 3>(Pb, Qb, 64, 64, lane, acc);   //  9 tiles
        else if (wv == 1) consume<3, 4>(Pb, Qb, 64,  0, lane, acc);   // 12
        else if (wv == 2) consume<4, 3>(Pb, Qb,  0, 64, lane, acc);   // 12
        else              consume<4, 4>(Pb, Qb,  0,  0, lane, acc);   // 16
        if (ch < 30)
            produce_t<8>(ch + 1, xs, Pl[(ch + 1) & 1], Ql[(ch + 1) & 1],
                         isPair, isCell, isVcol, tid, qrow, i1, i2, x0i, xL2, c1, c2, Ds);
        else if (ch == 30)
            produce_t<7>(31, xs, Pl[1], Ql[1],
                         isPair, isCell, isVcol, tid, qrow, i1, i2, x0i, xL2, c1, c2, Ds);
        __syncthreads();   // one barrier/chunk: separates read@ch from write@ch+2
    }

    // epilogue: [S1(10) | S2(100) | S3(1000) | S4(10000)]
    const size_t base = (size_t)b * SIG;
    if (tid < 10)  out[base + tid] = xs[2550 + tid] - xs[tid];   // S1 exact
    if (isPair)    out[base + 10 + tid] = Ds;                    // S2 exact

    const int r0 = (wv & 2) ? 0 : 64;
    const int c0 = (wv & 1) ? 0 : 64;
    #pragma unroll
    for (int mi = 0; mi < 4; ++mi) {
        #pragma unroll
        for (int ni = 0; ni < 4; ++ni) {
            #pragma unroll
            for (int r = 0; r < 4; ++r) {
                const int m = r0 + mi * 16 + (lane >> 4) * 4 + r;
                const int n = c0 + ni * 16 + (lane & 15);
                if (m < 100) {
                    if (n < 100)      out[base + 1110 + m * 100 + n]         = acc[mi][ni][r];
                    else if (n < 110) out[base + 110  + m * 10  + (n - 100)] = acc[mi][ni][r];
                }
            }
        }
    }
}

extern "C" void kernel_launch(void* const* d_in, const int* in_sizes, int n_in,
                              void* d_out, int out_size, void* d_ws, size_t ws_size,
                              hipStream_t stream) {
    const float* x = (const float*)d_in[0];
    float* out = (float*)d_out;
    const int B = in_sizes[0] / 2560;   // 2048 batches, one block each
    sig_mfma8<<<B, 256, 0, stream>>>(x, out);
}